// Round 6
// baseline (1379.966 us; speedup 1.0000x reference)
//
#include <hip/hip_runtime.h>
#include <math.h>

#define NB 10
#define PPC 29          // 3*NB-1
#define CCH 4
#define HID 64
#define HH 256
#define WW 256
#define BB 16
#define TB 1.0f
#define MINW 0.001f
#define MINH 0.001f
#define MIND 0.001f

#define ZTOT (BB*CCH*HH*WW)     // 4194304

// Tile: 8x8 pixels. M=64, N=128 (116 valid), K=576. 16384 blocks.
#define HALO_PIX 100            // 10 x 10
#define HSTR 72                 // s_hid row stride (bf16): 64 + 8 pad -> rows 144B (16B-aligned, b128 reads)
#define PSTR 117                // p_buf row stride (f32): odd -> conflict-free spline reads
#define NCOLS 116               // valid N columns; >=116 is zero-padding (never stored)
#define W2B_ELEMS (18*8*64*8)   // 73728 bf16 per copy; hi+lo = 294912 B in d_ws

typedef __attribute__((ext_vector_type(8))) short short8v;
typedef __attribute__((ext_vector_type(4))) float f32x4;

__device__ inline unsigned short f2bf(float f) {
    unsigned u = __float_as_uint(f);
    unsigned r = (u + 0x7FFFu + ((u >> 16) & 1u)) >> 16;
    return (unsigned short)r;
}
__device__ inline float bf2f(unsigned short s) {
    return __uint_as_float(((unsigned)s) << 16);
}

__global__ void zero_lad_kernel(float* out) {
    out[ZTOT + threadIdx.x] = 0.0f;
}

// Prepack W2 -> bf16 fragment order, hi/lo split for ~fp32 effective precision.
// w2b[copy(2)][kidx(18)][ntile(8)][lane(64)][j(8)]
// kidx = tap*2 + ks; n = ntile*16 + (lane&15); ci = ks*32 + (lane>>4)*8 + j
__global__ void prepack_w2(const float* __restrict__ W2, unsigned short* __restrict__ w2b) {
    int idx = blockIdx.x * 256 + threadIdx.x;
    if (idx >= W2B_ELEMS) return;
    int j    = idx & 7;
    int lane = (idx >> 3) & 63;
    int nt   = (idx >> 9) & 7;
    int kidx = idx >> 12;            // 0..17
    int tap  = kidx >> 1;
    int ks   = kidx & 1;
    int ky   = tap / 3;
    int kx   = tap - ky * 3;
    int n    = nt * 16 + (lane & 15);
    int ci   = ks * 32 + (lane >> 4) * 8 + j;
    float v = 0.0f;
    if (n < PPC * CCH) v = W2[((n * HID + ci) * 3 + ky) * 3 + kx];
    unsigned short hi = f2bf(v);
    float rem = v - bf2f(hi);
    w2b[idx]             = hi;
    w2b[idx + W2B_ELEMS] = f2bf(rem);
}

__global__ __launch_bounds__(256, 5)
void fused_kernel(const float* __restrict__ x, const float* __restrict__ clean,
                  const float* __restrict__ W1, const float* __restrict__ b1,
                  const float* __restrict__ b2, const unsigned short* __restrict__ w2b,
                  float* __restrict__ out)
{
    // Union region (29952 B = 64*PSTR f32):
    //   phases A-C: s_hid = 100*72 bf16 (14400 B) at float offset 0,
    //               s_clean = 4ch*12*12 f32 (2304 B) at float offset 3600.
    //   epilogue:   p_buf = 64 x PSTR f32 (overwrites both, barrier-ordered).
    __shared__ __align__(16) float s_un[64 * PSTR];
    __shared__ float s_red[4];

    unsigned short* s_hid   = (unsigned short*)s_un;
    float*          s_clean = s_un + 3600;

    const int tid  = threadIdx.x;
    const int blk  = blockIdx.x;
    const int b    = blk >> 10;
    const int ty   = (blk >> 5) & 31;
    const int tx   = blk & 31;
    const int Y0 = ty * 8, X0 = tx * 8;

    const int w    = tid >> 6;        // wave id == spline channel c
    const int lane = tid & 63;
    const int l15  = lane & 15;
    const int quad = lane >> 4;
    const int wy   = w & 1;           // M half: mtiles wy*2, wy*2+1
    const int wx   = w >> 1;          // N half: ntiles wx*4 .. wx*4+3

    // ---------- Phase A: stage clean tile (4ch x 12 x 12, zero-padded) ----------
    for (int i = tid; i < CCH*12*12; i += 256) {
        int c  = i / 144;
        int r  = i - c * 144;
        int cy = r / 12;
        int cx = r - cy * 12;
        int iy = Y0 - 2 + cy, ix = X0 - 2 + cx;
        float v = 0.0f;
        if (iy >= 0 && iy < HH && ix >= 0 && ix < WW)
            v = clean[((b*CCH + c) << 16) + iy*WW + ix];
        s_clean[i] = v;
    }
    __syncthreads();

    // ---------- Phase B: hid = relu(conv1(clean)) on 10x10 halo -> s_hid bf16 ----------
    // 200 threads: (pixel, co-half) -> 32 channels each (halves conv1 critical path).
    if (tid < 2*HALO_PIX) {
        int pix  = tid >> 1;
        int half = tid & 1;
        int hy = pix / 10, hx = pix - hy * 10;
        int iy = Y0 - 1 + hy, ix = X0 - 1 + hx;
        bool valid = (iy >= 0 && iy < HH && ix >= 0 && ix < WW);
        float cwin[36];
        #pragma unroll
        for (int c = 0; c < 4; ++c)
            #pragma unroll
            for (int ky = 0; ky < 3; ++ky)
                #pragma unroll
                for (int kx = 0; kx < 3; ++kx)
                    cwin[c*9 + ky*3 + kx] = s_clean[c*144 + (hy+ky)*12 + (hx+kx)];
        for (int cog = 0; cog < 4; ++cog) {
            float a8[8];
            #pragma unroll
            for (int coi = 0; coi < 8; ++coi) {
                int co = half*32 + cog*8 + coi;
                const float4* wv = (const float4*)(W1 + co*36);
                float a = b1[co];
                #pragma unroll
                for (int q = 0; q < 9; ++q) {
                    float4 t4 = wv[q];
                    a += t4.x*cwin[q*4] + t4.y*cwin[q*4+1] + t4.z*cwin[q*4+2] + t4.w*cwin[q*4+3];
                }
                a8[coi] = valid ? fmaxf(a, 0.0f) : 0.0f;
            }
            uint4 pk;
            pk.x = (unsigned)f2bf(a8[0]) | ((unsigned)f2bf(a8[1]) << 16);
            pk.y = (unsigned)f2bf(a8[2]) | ((unsigned)f2bf(a8[3]) << 16);
            pk.z = (unsigned)f2bf(a8[4]) | ((unsigned)f2bf(a8[5]) << 16);
            pk.w = (unsigned)f2bf(a8[6]) | ((unsigned)f2bf(a8[7]) << 16);
            *(uint4*)(&s_hid[pix*HSTR + half*32 + cog*8]) = pk;   // 16B-aligned
        }
    }
    __syncthreads();

    // ---------- Phase C: conv2 as implicit GEMM via MFMA (B = W2_hi + W2_lo) ----------
    // Wave (wy,wx): 2 mtiles x 4 ntiles = 8 acc tiles (32 f32/thread).
    f32x4 acc[2][4];
    #pragma unroll
    for (int mi = 0; mi < 2; ++mi)
        #pragma unroll
        for (int t = 0; t < 4; ++t) {
            acc[mi][t][0] = 0.f; acc[mi][t][1] = 0.f;
            acc[mi][t][2] = 0.f; acc[mi][t][3] = 0.f;
        }

    const short8v* __restrict__ wbv_hi = (const short8v*)w2b;
    const short8v* __restrict__ wbv_lo = (const short8v*)(w2b + W2B_ELEMS);

    // A-row mapping: pixel p = mtile*16 + l15; py = p>>3, px = p&7.
    const int px8 = l15 & 7;
    const int py0 = wy*4 + (l15 >> 3);     // mtile wy*2+0
    const int py1 = py0 + 2;               // mtile wy*2+1

    for (int tap = 0; tap < 9; ++tap) {
        int ky = tap / 3;
        int kx = tap - ky * 3;
        int r0 = ((py0 + ky)*10 + px8 + kx)*HSTR + quad*8;
        int r1 = ((py1 + ky)*10 + px8 + kx)*HSTR + quad*8;
        #pragma unroll
        for (int ks = 0; ks < 2; ++ks) {
            int boff = ((tap*2 + ks)*8 + wx*4)*64 + lane;
            short8v bfr[4];
            #pragma unroll
            for (int t = 0; t < 4; ++t)
                bfr[t] = wbv_hi[boff + t*64];
            short8v a0 = *(const short8v*)(s_hid + r0 + ks*32);   // ds_read_b128
            short8v a1 = *(const short8v*)(s_hid + r1 + ks*32);
            #pragma unroll
            for (int t = 0; t < 4; ++t) {
                acc[0][t] = __builtin_amdgcn_mfma_f32_16x16x32_bf16(a0, bfr[t], acc[0][t], 0, 0, 0);
                acc[1][t] = __builtin_amdgcn_mfma_f32_16x16x32_bf16(a1, bfr[t], acc[1][t], 0, 0, 0);
            }
            #pragma unroll
            for (int t = 0; t < 4; ++t)
                bfr[t] = wbv_lo[boff + t*64];
            #pragma unroll
            for (int t = 0; t < 4; ++t) {
                acc[0][t] = __builtin_amdgcn_mfma_f32_16x16x32_bf16(a0, bfr[t], acc[0][t], 0, 0, 0);
                acc[1][t] = __builtin_amdgcn_mfma_f32_16x16x32_bf16(a1, bfr[t], acc[1][t], 0, 0, 0);
            }
        }
    }

    // ---------- Epilogue: all acc -> p_buf (aliases s_hid/s_clean), then spline ----------
    float* p_buf = s_un;
    const float* b2c = b2 + w * PPC;      // wave-uniform -> scalar loads

    __syncthreads();   // all s_hid MFMA reads complete before p_buf overwrites
    #pragma unroll
    for (int mi = 0; mi < 2; ++mi) {
        #pragma unroll
        for (int t = 0; t < 4; ++t) {
            int col = (wx*4 + t)*16 + l15;
            if (col < NCOLS) {    // cols >=116 are padding; would wrap PSTR (R3 bug)
                f32x4 v = acc[mi][t];
                int base = ((wy*2 + mi)*16 + quad*4) * PSTR + col;
                p_buf[base]          = v[0];
                p_buf[base + PSTR]   = v[1];
                p_buf[base + 2*PSTR] = v[2];
                p_buf[base + 3*PSTR] = v[3];
            }
        }
    }
    __syncthreads();

    // spline: thread -> (c = w, pixel = lane); all 256 threads active, single pass
    float pv[PPC];
    #pragma unroll
    for (int j = 0; j < PPC; ++j)
        pv[j] = p_buf[lane * PSTR + w * PPC + j];

    const float scale = 0.125f;   // 1/sqrt(HIDDEN)
    float uw[NB], uh[NB], ud9[NB-1];
    #pragma unroll
    for (int j = 0; j < NB; ++j)   uw[j]  = (pv[j]      + b2c[j])      * scale;
    #pragma unroll
    for (int j = 0; j < NB; ++j)   uh[j]  = (pv[NB+j]   + b2c[NB+j])   * scale;
    #pragma unroll
    for (int j = 0; j < NB-1; ++j) ud9[j] =  pv[2*NB+j] + b2c[2*NB+j];

    float mw = uw[0];
    #pragma unroll
    for (int j = 1; j < NB; ++j) mw = fmaxf(mw, uw[j]);
    float sw = 0.0f;
    #pragma unroll
    for (int j = 0; j < NB; ++j) { uw[j] = __expf(uw[j] - mw); sw += uw[j]; }
    float isw = 1.0f / sw;
    float cw[NB+1];
    cw[0] = -TB;
    float run = 0.0f;
    #pragma unroll
    for (int j = 0; j < NB; ++j) {
        float wj = MINW + (1.0f - MINW*NB) * (uw[j] * isw);
        run += wj;
        cw[j+1] = -TB + 2.0f*TB*run;
    }
    cw[NB] = TB;

    float mh = uh[0];
    #pragma unroll
    for (int j = 1; j < NB; ++j) mh = fmaxf(mh, uh[j]);
    float sh = 0.0f;
    #pragma unroll
    for (int j = 0; j < NB; ++j) { uh[j] = __expf(uh[j] - mh); sh += uh[j]; }
    float ish = 1.0f / sh;
    float chh[NB+1];
    chh[0] = -TB;
    float runh = 0.0f;
    #pragma unroll
    for (int j = 0; j < NB; ++j) {
        float hj = MINH + (1.0f - MINH*NB) * (uh[j] * ish);
        runh += hj;
        chh[j+1] = -TB + 2.0f*TB*runh;
    }
    chh[NB] = TB;

    float dv[NB+1];
    dv[0] = 1.0f; dv[NB] = 1.0f;
    #pragma unroll
    for (int k = 0; k < NB-1; ++k) {
        float v = ud9[k];
        // softplus via fast intrinsics: exp(-|v|) tiny -> 1+t rounds to 1 -> log 0,
        // matching the log1p asymptote
        float sp = fmaxf(v, 0.0f) + __logf(1.0f + __expf(-fabsf(v)));
        dv[k+1] = MIND + sp;
    }

    int py = lane >> 3, px = lane & 7;
    int gidx = ((b*CCH + w) << 16) + (Y0 + py)*WW + (X0 + px);
    float xv  = x[gidx];
    float xin = fminf(fmaxf(xv, -TB), TB);
    int cnt = 0;
    #pragma unroll
    for (int k = 0; k <= NB; ++k) cnt += (xin >= cw[k]) ? 1 : 0;
    int idx = cnt - 1;
    idx = idx < 0 ? 0 : (idx > NB-1 ? NB-1 : idx);

    float icw = cw[0], inw = cw[1], ich = chh[0], inh = chh[1], d0 = dv[0], d1 = dv[1];
    #pragma unroll
    for (int k = 1; k < NB; ++k) {
        bool m = (idx == k);
        icw = m ? cw[k]    : icw;
        inw = m ? cw[k+1]  : inw;
        ich = m ? chh[k]   : ich;
        inh = m ? chh[k+1] : inh;
        d0  = m ? dv[k]    : d0;
        d1  = m ? dv[k+1]  : d1;
    }
    float ibw = inw - icw;
    float ihh = inh - ich;
    float idl = ihh / ibw;
    float th  = (xin - icw) / ibw;
    float omt = 1.0f - th;
    float tt  = th * omt;
    float numer = ihh * (idl*th*th + d0*tt);
    float den   = idl + (d0 + d1 - 2.0f*idl)*tt;
    float z_in  = ich + numer/den;
    float dnum  = idl*idl*(d1*th*th + 2.0f*idl*tt + d0*omt*omt);
    float lad_in = __logf(dnum) - 2.0f*__logf(den);
    bool inside = (xv >= -TB) && (xv <= TB);
    float z = inside ? z_in : xv;
    float lad = inside ? lad_in : 0.0f;
    out[gidx] = z;

    // ---------- block-reduce lad, one atomic per block ----------
    #pragma unroll
    for (int off = 32; off >= 1; off >>= 1)
        lad += __shfl_xor(lad, off, 64);
    if (lane == 0) s_red[w] = lad;
    __syncthreads();
    if (tid == 0)
        atomicAdd(out + ZTOT + b, s_red[0] + s_red[1] + s_red[2] + s_red[3]);
}

extern "C" void kernel_launch(void* const* d_in, const int* in_sizes, int n_in,
                              void* d_out, int out_size, void* d_ws, size_t ws_size,
                              hipStream_t stream) {
    const float* x     = (const float*)d_in[0];
    const float* clean = (const float*)d_in[1];
    const float* W1    = (const float*)d_in[2];
    const float* b1    = (const float*)d_in[3];
    const float* W2    = (const float*)d_in[4];
    const float* b2    = (const float*)d_in[5];
    float* out = (float*)d_out;
    unsigned short* w2b = (unsigned short*)d_ws;   // 294912 B (hi + lo copies)

    zero_lad_kernel<<<1, 16, 0, stream>>>(out);
    prepack_w2<<<(W2B_ELEMS + 255)/256, 256, 0, stream>>>(W2, w2b);
    fused_kernel<<<BB*32*32, 256, 0, stream>>>(x, clean, W1, b1, b2, w2b, out);
}

// Round 7
// 528.826 us; speedup vs baseline: 2.6095x; 2.6095x over previous
//
#include <hip/hip_runtime.h>
#include <math.h>

#define NB 10
#define PPC 29          // 3*NB-1
#define CCH 4
#define HID 64
#define HH 256
#define WW 256
#define BB 16
#define TB 1.0f
#define MINW 0.001f
#define MINH 0.001f
#define MIND 0.001f

#define ZTOT (BB*CCH*HH*WW)     // 4194304

// Tile: 8x8 pixels. M=64, N=128 (116 valid), K=576. 16384 blocks.
#define HALO_PIX 100            // 10 x 10
#define HSTR 72                 // s_hid row stride (bf16): 64 + 8 pad -> rows 144B (16B-aligned, b128 reads)
#define PSTR 117                // p_buf row stride (f32): odd -> conflict-free spline reads
#define NCOLS 116               // valid N columns; >=116 is zero-padding (never stored)
#define W2B_ELEMS (18*8*64*8)   // 73728 bf16 per copy; hi+lo = 294912 B in d_ws

typedef __attribute__((ext_vector_type(8))) short short8v;
typedef __attribute__((ext_vector_type(4))) float f32x4;

__device__ inline unsigned short f2bf(float f) {
    unsigned u = __float_as_uint(f);
    unsigned r = (u + 0x7FFFu + ((u >> 16) & 1u)) >> 16;
    return (unsigned short)r;
}
__device__ inline float bf2f(unsigned short s) {
    return __uint_as_float(((unsigned)s) << 16);
}

__global__ void zero_lad_kernel(float* out) {
    out[ZTOT + threadIdx.x] = 0.0f;
}

// Prepack W2 -> bf16 fragment order, hi/lo split for ~fp32 effective precision.
// w2b[copy(2)][kidx(18)][ntile(8)][lane(64)][j(8)]
// kidx = tap*2 + ks; n = ntile*16 + (lane&15); ci = ks*32 + (lane>>4)*8 + j
__global__ void prepack_w2(const float* __restrict__ W2, unsigned short* __restrict__ w2b) {
    int idx = blockIdx.x * 256 + threadIdx.x;
    if (idx >= W2B_ELEMS) return;
    int j    = idx & 7;
    int lane = (idx >> 3) & 63;
    int nt   = (idx >> 9) & 7;
    int kidx = idx >> 12;            // 0..17
    int tap  = kidx >> 1;
    int ks   = kidx & 1;
    int ky   = tap / 3;
    int kx   = tap - ky * 3;
    int n    = nt * 16 + (lane & 15);
    int ci   = ks * 32 + (lane >> 4) * 8 + j;
    float v = 0.0f;
    if (n < PPC * CCH) v = W2[((n * HID + ci) * 3 + ky) * 3 + kx];
    unsigned short hi = f2bf(v);
    float rem = v - bf2f(hi);
    w2b[idx]             = hi;
    w2b[idx + W2B_ELEMS] = f2bf(rem);
}

__global__ __launch_bounds__(256, 5)
void fused_kernel(const float* __restrict__ x, const float* __restrict__ clean,
                  const float* __restrict__ W1, const float* __restrict__ b1,
                  const float* __restrict__ b2, const unsigned short* __restrict__ w2b,
                  float* __restrict__ out)
{
    // Union region (29952 B = 64*PSTR f32):
    //   phases A-C: s_hid = 100*72 bf16 (14400 B) at float offset 0,
    //               s_clean = 4ch*12*12 f32 (2304 B) at float offset 3600.
    //   epilogue:   p_buf = 64 x PSTR f32 (overwrites both, barrier-ordered).
    __shared__ __align__(16) float s_un[64 * PSTR];
    __shared__ float s_red[4];

    unsigned short* s_hid   = (unsigned short*)s_un;
    float*          s_clean = s_un + 3600;

    const int tid  = threadIdx.x;
    const int blk  = blockIdx.x;
    const int b    = blk >> 10;
    const int ty   = (blk >> 5) & 31;
    const int tx   = blk & 31;
    const int Y0 = ty * 8, X0 = tx * 8;

    const int w    = tid >> 6;        // wave id == spline channel c == N-quarter
    const int lane = tid & 63;
    const int l15  = lane & 15;
    const int quad = lane >> 4;

    // ---------- Phase A: stage clean tile (4ch x 12 x 12, zero-padded) ----------
    for (int i = tid; i < CCH*12*12; i += 256) {
        int c  = i / 144;
        int r  = i - c * 144;
        int cy = r / 12;
        int cx = r - cy * 12;
        int iy = Y0 - 2 + cy, ix = X0 - 2 + cx;
        float v = 0.0f;
        if (iy >= 0 && iy < HH && ix >= 0 && ix < WW)
            v = clean[((b*CCH + c) << 16) + iy*WW + ix];
        s_clean[i] = v;
    }
    __syncthreads();

    // ---------- Phase B: hid = relu(conv1(clean)) on 10x10 halo -> s_hid bf16 ----------
    // Pixel-per-thread; co loop is WAVE-UNIFORM so W1 reads stay scalar s_loads
    // (R6 made co tid-dependent -> vector loads -> 15 GB L2 traffic regression).
    if (tid < HALO_PIX) {
        int hy = tid / 10, hx = tid - hy * 10;
        int iy = Y0 - 1 + hy, ix = X0 - 1 + hx;
        bool valid = (iy >= 0 && iy < HH && ix >= 0 && ix < WW);
        float cwin[36];
        #pragma unroll
        for (int c = 0; c < 4; ++c)
            #pragma unroll
            for (int ky = 0; ky < 3; ++ky)
                #pragma unroll
                for (int kx = 0; kx < 3; ++kx)
                    cwin[c*9 + ky*3 + kx] = s_clean[c*144 + (hy+ky)*12 + (hx+kx)];
        for (int cog = 0; cog < 8; ++cog) {
            float a8[8];
            #pragma unroll
            for (int coi = 0; coi < 8; ++coi) {
                int co = cog*8 + coi;                           // uniform
                const float4* wv = (const float4*)(W1 + co*36); // -> s_load
                float a = b1[co];
                #pragma unroll
                for (int q = 0; q < 9; ++q) {
                    float4 t4 = wv[q];
                    a += t4.x*cwin[q*4] + t4.y*cwin[q*4+1] + t4.z*cwin[q*4+2] + t4.w*cwin[q*4+3];
                }
                a8[coi] = valid ? fmaxf(a, 0.0f) : 0.0f;
            }
            uint4 pk;
            pk.x = (unsigned)f2bf(a8[0]) | ((unsigned)f2bf(a8[1]) << 16);
            pk.y = (unsigned)f2bf(a8[2]) | ((unsigned)f2bf(a8[3]) << 16);
            pk.z = (unsigned)f2bf(a8[4]) | ((unsigned)f2bf(a8[5]) << 16);
            pk.w = (unsigned)f2bf(a8[6]) | ((unsigned)f2bf(a8[7]) << 16);
            *(uint4*)(&s_hid[tid*HSTR + cog*8]) = pk;   // 16B-aligned
        }
    }
    __syncthreads();

    // ---------- Phase C: conv2 as implicit GEMM via MFMA (B = W2_hi + W2_lo) ----------
    // Wave w: ntiles {2w, 2w+1} x all 4 mtiles = 8 acc tiles (32 f32/thread).
    // No ntile is read by two waves -> per-block B-traffic = 294912 B (R6 had 2x dup).
    f32x4 acc[4][2];
    #pragma unroll
    for (int mi = 0; mi < 4; ++mi)
        #pragma unroll
        for (int t = 0; t < 2; ++t) {
            acc[mi][t][0] = 0.f; acc[mi][t][1] = 0.f;
            acc[mi][t][2] = 0.f; acc[mi][t][3] = 0.f;
        }

    const short8v* __restrict__ wbv_hi = (const short8v*)w2b;
    const short8v* __restrict__ wbv_lo = (const short8v*)(w2b + W2B_ELEMS);

    // A-row mapping: pixel p = mi*16 + l15; py = mi*2 + (l15>>3), px = l15&7.
    const int px8 = l15 & 7;
    const int pyb = l15 >> 3;

    for (int tap = 0; tap < 9; ++tap) {
        int ky = tap / 3;
        int kx = tap - ky * 3;
        int r0 = ((pyb + ky)*10 + px8 + kx)*HSTR + quad*8;
        #pragma unroll
        for (int ks = 0; ks < 2; ++ks) {
            int boff = ((tap*2 + ks)*8 + w*2)*64 + lane;
            short8v bh0 = wbv_hi[boff];
            short8v bh1 = wbv_hi[boff + 64];
            short8v afr[4];
            #pragma unroll
            for (int mi = 0; mi < 4; ++mi)
                afr[mi] = *(const short8v*)(s_hid + r0 + mi*(2*10*HSTR) + ks*32);  // ds_read_b128
            #pragma unroll
            for (int mi = 0; mi < 4; ++mi) {
                acc[mi][0] = __builtin_amdgcn_mfma_f32_16x16x32_bf16(afr[mi], bh0, acc[mi][0], 0, 0, 0);
                acc[mi][1] = __builtin_amdgcn_mfma_f32_16x16x32_bf16(afr[mi], bh1, acc[mi][1], 0, 0, 0);
            }
            short8v bl0 = wbv_lo[boff];
            short8v bl1 = wbv_lo[boff + 64];
            #pragma unroll
            for (int mi = 0; mi < 4; ++mi) {
                acc[mi][0] = __builtin_amdgcn_mfma_f32_16x16x32_bf16(afr[mi], bl0, acc[mi][0], 0, 0, 0);
                acc[mi][1] = __builtin_amdgcn_mfma_f32_16x16x32_bf16(afr[mi], bl1, acc[mi][1], 0, 0, 0);
            }
        }
    }

    // ---------- Epilogue: all acc -> p_buf (aliases s_hid/s_clean), then spline ----------
    float* p_buf = s_un;
    const float* b2c = b2 + w * PPC;      // wave-uniform -> scalar loads

    __syncthreads();   // all s_hid MFMA reads complete before p_buf overwrites
    #pragma unroll
    for (int mi = 0; mi < 4; ++mi) {
        #pragma unroll
        for (int t = 0; t < 2; ++t) {
            int col = (w*2 + t)*16 + l15;
            if (col < NCOLS) {    // cols >=116 are padding; would wrap PSTR (R3 bug)
                f32x4 v = acc[mi][t];
                int base = (mi*16 + quad*4) * PSTR + col;
                p_buf[base]          = v[0];
                p_buf[base + PSTR]   = v[1];
                p_buf[base + 2*PSTR] = v[2];
                p_buf[base + 3*PSTR] = v[3];
            }
        }
    }
    __syncthreads();

    // spline: thread -> (c = w, pixel = lane); all 256 threads active, single pass
    float pv[PPC];
    #pragma unroll
    for (int j = 0; j < PPC; ++j)
        pv[j] = p_buf[lane * PSTR + w * PPC + j];

    const float scale = 0.125f;   // 1/sqrt(HIDDEN)
    float uw[NB], uh[NB], ud9[NB-1];
    #pragma unroll
    for (int j = 0; j < NB; ++j)   uw[j]  = (pv[j]      + b2c[j])      * scale;
    #pragma unroll
    for (int j = 0; j < NB; ++j)   uh[j]  = (pv[NB+j]   + b2c[NB+j])   * scale;
    #pragma unroll
    for (int j = 0; j < NB-1; ++j) ud9[j] =  pv[2*NB+j] + b2c[2*NB+j];

    float mw = uw[0];
    #pragma unroll
    for (int j = 1; j < NB; ++j) mw = fmaxf(mw, uw[j]);
    float sw = 0.0f;
    #pragma unroll
    for (int j = 0; j < NB; ++j) { uw[j] = __expf(uw[j] - mw); sw += uw[j]; }
    float isw = 1.0f / sw;
    float cw[NB+1];
    cw[0] = -TB;
    float run = 0.0f;
    #pragma unroll
    for (int j = 0; j < NB; ++j) {
        float wj = MINW + (1.0f - MINW*NB) * (uw[j] * isw);
        run += wj;
        cw[j+1] = -TB + 2.0f*TB*run;
    }
    cw[NB] = TB;

    float mh = uh[0];
    #pragma unroll
    for (int j = 1; j < NB; ++j) mh = fmaxf(mh, uh[j]);
    float sh = 0.0f;
    #pragma unroll
    for (int j = 0; j < NB; ++j) { uh[j] = __expf(uh[j] - mh); sh += uh[j]; }
    float ish = 1.0f / sh;
    float chh[NB+1];
    chh[0] = -TB;
    float runh = 0.0f;
    #pragma unroll
    for (int j = 0; j < NB; ++j) {
        float hj = MINH + (1.0f - MINH*NB) * (uh[j] * ish);
        runh += hj;
        chh[j+1] = -TB + 2.0f*TB*runh;
    }
    chh[NB] = TB;

    float dv[NB+1];
    dv[0] = 1.0f; dv[NB] = 1.0f;
    #pragma unroll
    for (int k = 0; k < NB-1; ++k) {
        float v = ud9[k];
        // softplus via fast intrinsics: exp(-|v|) tiny -> 1+t rounds to 1 -> log 0,
        // matching the log1p asymptote
        float sp = fmaxf(v, 0.0f) + __logf(1.0f + __expf(-fabsf(v)));
        dv[k+1] = MIND + sp;
    }

    int py = lane >> 3, px = lane & 7;
    int gidx = ((b*CCH + w) << 16) + (Y0 + py)*WW + (X0 + px);
    float xv  = x[gidx];
    float xin = fminf(fmaxf(xv, -TB), TB);
    int cnt = 0;
    #pragma unroll
    for (int k = 0; k <= NB; ++k) cnt += (xin >= cw[k]) ? 1 : 0;
    int idx = cnt - 1;
    idx = idx < 0 ? 0 : (idx > NB-1 ? NB-1 : idx);

    float icw = cw[0], inw = cw[1], ich = chh[0], inh = chh[1], d0 = dv[0], d1 = dv[1];
    #pragma unroll
    for (int k = 1; k < NB; ++k) {
        bool m = (idx == k);
        icw = m ? cw[k]    : icw;
        inw = m ? cw[k+1]  : inw;
        ich = m ? chh[k]   : ich;
        inh = m ? chh[k+1] : inh;
        d0  = m ? dv[k]    : d0;
        d1  = m ? dv[k+1]  : d1;
    }
    float ibw = inw - icw;
    float ihh = inh - ich;
    float idl = ihh / ibw;
    float th  = (xin - icw) / ibw;
    float omt = 1.0f - th;
    float tt  = th * omt;
    float numer = ihh * (idl*th*th + d0*tt);
    float den   = idl + (d0 + d1 - 2.0f*idl)*tt;
    float z_in  = ich + numer/den;
    float dnum  = idl*idl*(d1*th*th + 2.0f*idl*tt + d0*omt*omt);
    float lad_in = __logf(dnum) - 2.0f*__logf(den);
    bool inside = (xv >= -TB) && (xv <= TB);
    float z = inside ? z_in : xv;
    float lad = inside ? lad_in : 0.0f;
    out[gidx] = z;

    // ---------- block-reduce lad, one atomic per block ----------
    #pragma unroll
    for (int off = 32; off >= 1; off >>= 1)
        lad += __shfl_xor(lad, off, 64);
    if (lane == 0) s_red[w] = lad;
    __syncthreads();
    if (tid == 0)
        atomicAdd(out + ZTOT + b, s_red[0] + s_red[1] + s_red[2] + s_red[3]);
}

extern "C" void kernel_launch(void* const* d_in, const int* in_sizes, int n_in,
                              void* d_out, int out_size, void* d_ws, size_t ws_size,
                              hipStream_t stream) {
    const float* x     = (const float*)d_in[0];
    const float* clean = (const float*)d_in[1];
    const float* W1    = (const float*)d_in[2];
    const float* b1    = (const float*)d_in[3];
    const float* W2    = (const float*)d_in[4];
    const float* b2    = (const float*)d_in[5];
    float* out = (float*)d_out;
    unsigned short* w2b = (unsigned short*)d_ws;   // 294912 B (hi + lo copies)

    zero_lad_kernel<<<1, 16, 0, stream>>>(out);
    prepack_w2<<<(W2B_ELEMS + 255)/256, 256, 0, stream>>>(W2, w2b);
    fused_kernel<<<BB*32*32, 256, 0, stream>>>(x, clean, W1, b1, b2, w2b, out);
}